// Round 18
// baseline (51.025 us; speedup 1.0000x reference)
//
#include <hip/hip_runtime.h>
#include <hip/hip_fp16.h>

#define NC 16384        // num classes == batch
#define FD 128          // feature dim
#define LAMBDA 0.005f
#define SLOTCAP 64      // max samples tracked per class (Poisson(1): max ~10)
#define NPAIR 128       // 128-row pairs (2x64 chunks) per matrix
#define NGB (2 * NPAIR) // 256 gram blocks
#define NRB 128         // reduce participants (last NRB tickets)

typedef __attribute__((ext_vector_type(8))) short short8;  // 8 bf16 (4 VGPRs)
typedef __attribute__((ext_vector_type(4))) float f32x4;   // MFMA acc

__device__ __forceinline__ float wave_sum(float v) {
#pragma unroll
  for (int m = 32; m > 0; m >>= 1) v += __shfl_xor(v, m, 64);
  return v;
}

__device__ __forceinline__ unsigned pack_bf16(float x, float y) {
  unsigned ux = __float_as_uint(x), uy = __float_as_uint(y);
  ux = (ux + 0x7FFFu + ((ux >> 16) & 1u)) >> 16;  // RNE f32->bf16
  uy = (uy + 0x7FFFu + ((uy >> 16) & 1u)) >> 16;
  return ux | (uy << 16);
}

// --- 1. zero cnt + scal ---------------------------------------------------------
__global__ __launch_bounds__(256) void zero_kernel(int4* __restrict__ cnt4,
                                                   float* __restrict__ scal) {
  cnt4[blockIdx.x * 256 + threadIdx.x] = make_int4(0, 0, 0, 0);
  if (blockIdx.x == 0 && threadIdx.x < 16) scal[threadIdx.x] = 0.f;
}

// --- 2. scatter: slot[lab][k] = sample index --------------------------------------
__global__ __launch_bounds__(256) void scatter_kernel(
    const int* __restrict__ labels, int* __restrict__ cnt, int* __restrict__ slot) {
  int i = blockIdx.x * 256 + threadIdx.x;
  int lab = labels[i];
  int p = atomicAdd(&cnt[lab], 1);
  if (p < SLOTCAP) slot[(size_t)lab * SLOTCAP + p] = i;
}

// --- 3. centers + diag -> bf16 zn/cn (R15 verbatim: 1 class/wave, 4096 blocks) -----
__global__ __launch_bounds__(256) void center_kernel(
    const float* __restrict__ z, const int* __restrict__ cnt,
    const int* __restrict__ slot, unsigned* __restrict__ cnb,
    unsigned* __restrict__ znb, float2* __restrict__ dpart) {
  __shared__ float red[8];
  int t = threadIdx.x, wave = t >> 6, lane = t & 63;
  int c = blockIdx.x * 4 + wave;

  // independent loads issued together: slot int4, cnt, diag z row
  int4 s4 = *(const int4*)&slot[(size_t)c * SLOTCAP];
  int n = cnt[c];
  float2 a = *(const float2*)&z[(size_t)c * FD + lane * 2];
  if (n > SLOTCAP) n = SLOTCAP;

  // up to 4 gathered rows in parallel (predicated index; safe dummy = row c)
  int i0 = n > 0 ? s4.x : c, i1 = n > 1 ? s4.y : c;
  int i2 = n > 2 ? s4.z : c, i3 = n > 3 ? s4.w : c;
  float2 v0 = *(const float2*)&z[(size_t)i0 * FD + lane * 2];
  float2 v1 = *(const float2*)&z[(size_t)i1 * FD + lane * 2];
  float2 v2 = *(const float2*)&z[(size_t)i2 * FD + lane * 2];
  float2 v3 = *(const float2*)&z[(size_t)i3 * FD + lane * 2];
  float2 s = make_float2(0.f, 0.f);
  if (n > 0) { s.x += v0.x; s.y += v0.y; }
  if (n > 1) { s.x += v1.x; s.y += v1.y; }
  if (n > 2) { s.x += v2.x; s.y += v2.y; }
  if (n > 3) { s.x += v3.x; s.y += v3.y; }
  for (int k = 4; k < n; ++k) {  // rare (Poisson(1) tail)
    int i = slot[(size_t)c * SLOTCAP + k];
    float2 v = *(const float2*)&z[(size_t)i * FD + lane * 2];
    s.x += v.x; s.y += v.y;
  }
  float inv = n > 0 ? 1.0f / (float)n : 0.0f;
  s.x *= inv; s.y *= inv;
  float sc = wave_sum(s.x * s.x + s.y * s.y);
  float ic = 1.0f / fmaxf(sqrtf(sc), 1e-12f);
  s.x *= ic; s.y *= ic;
  cnb[(size_t)c * 64 + lane] = pack_bf16(s.x, s.y);

  // diag + normalized z row out
  float na = wave_sum(a.x * a.x + a.y * a.y);
  float ia = 1.0f / fmaxf(sqrtf(na), 1e-12f);
  float dd = wave_sum(a.x * s.x + a.y * s.y);
  float d = dd * ia;
  znb[(size_t)c * 64 + lane] = pack_bf16(a.x * ia, a.y * ia);

  if (lane == 0) { red[wave * 2] = d; red[wave * 2 + 1] = d * d; }
  __syncthreads();
  if (t == 0) {
    dpart[blockIdx.x] = make_float2(red[0] + red[2] + red[4] + red[6],
                                    red[1] + red[3] + red[5] + red[7]);
  }
}

// --- 4. gram (MFMA, 2 chunks/block) + quorum-merged reduce + final loss ------------
// Phase G (256 blocks): partial G for (matrix m=b&1, pair=b>>1), fp16 store.
// Then ticket; tickets >= 128 spin until all 256 arrived, run reduce slice
// rblk = ticket-128 (exact R15 reduce_final body); inner ticket composes loss.
__global__ __launch_bounds__(256) void gram_reduce_kernel(
    const unsigned short* __restrict__ znb, const unsigned short* __restrict__ cnb,
    __half2* __restrict__ pz, __half2* __restrict__ pc,
    const float2* __restrict__ dpart, float* __restrict__ scal,
    int* __restrict__ ticket_p, int* __restrict__ qc, float* __restrict__ out) {
  __shared__ char lds[33280];
  unsigned short* Bu = (unsigned short*)lds;  // B0 @0, B1 @8320 (u16 units)
  int t = threadIdx.x, wave = t >> 6, lane = t & 63;
  int b = blockIdx.x, m = b & 1, pair = b >> 1;
  const unsigned short* Ab = m ? cnb : znb;

  {  // stage both 64x128 bf16 chunks, coalesced int4 (32 KB total)
    const int4* src = (const int4*)(Ab + (size_t)pair * 16384);
#pragma unroll
    for (int k = 0; k < 8; ++k) {
      int idx = k * 256 + t;
      int q = idx >> 10, idx2 = idx & 1023;
      int row = idx2 >> 4, col8 = idx2 & 15;
      *(int4*)&Bu[q * 8320 + row * 130 + col8 * 8] = src[idx];
    }
  }
  __syncthreads();

  f32x4 acc[2][8];
#pragma unroll
  for (int i = 0; i < 2; ++i)
#pragma unroll
    for (int j = 0; j < 8; ++j)
      acc[i][j] = (f32x4){0.f, 0.f, 0.f, 0.f};

#pragma unroll
  for (int q = 0; q < 2; ++q) {
    const unsigned short* Bl = Bu + q * 8320 + (lane >> 4) * (8 * 130) + (lane & 15);
    short8 fr[2][8];
#pragma unroll
    for (int kb = 0; kb < 2; ++kb)
#pragma unroll
      for (int cb = 0; cb < 8; ++cb)
#pragma unroll
        for (int j = 0; j < 8; ++j)
          fr[kb][cb][j] = (short)Bl[kb * 4160 + cb * 16 + j * 130];
    short8 fa[2][2];
#pragma unroll
    for (int til = 0; til < 2; ++til)
#pragma unroll
      for (int kb = 0; kb < 2; ++kb)
#pragma unroll
        for (int j = 0; j < 8; ++j)
          fa[til][kb][j] = (short)Bl[kb * 4160 + (wave * 2 + til) * 16 + j * 130];
#pragma unroll
    for (int til = 0; til < 2; ++til)
#pragma unroll
      for (int tj = 0; tj < 8; ++tj) {
        acc[til][tj] = __builtin_amdgcn_mfma_f32_16x16x32_bf16(
            fa[til][0], fr[0][tj], acc[til][tj], 0, 0, 0);
        acc[til][tj] = __builtin_amdgcn_mfma_f32_16x16x32_bf16(
            fa[til][1], fr[1][tj], acc[til][tj], 0, 0, 0);
      }
  }
  __syncthreads();  // all frag reads done; safe to alias G over B0/B1

  unsigned short* G = (unsigned short*)lds;  // fp16 [128][130]
#pragma unroll
  for (int til = 0; til < 2; ++til)
#pragma unroll
    for (int tj = 0; tj < 8; ++tj)
#pragma unroll
      for (int q = 0; q < 4; ++q) {
        int d = (wave * 2 + til) * 16 + (lane >> 4) * 4 + q;  // C/D row=(l>>4)*4+reg
        int e = tj * 16 + (lane & 15);                        //     col=l&15
        __half h = __float2half(acc[til][tj][q]);
        G[d * 130 + e] = *(unsigned short*)&h;
      }
  __syncthreads();

  // coalesced partial copy-out: [128][64 half2] row-major
  unsigned* Pg = (unsigned*)((m ? pc : pz) + (size_t)pair * 8192);
#pragma unroll
  for (int it = 0; it < 32; ++it) {
    int row = it * 4 + (t >> 6);
    int h2i = t & 63;
    Pg[row * 64 + h2i] = *(const unsigned*)(lds + row * 260 + h2i * 4);
  }

  // ---- quorum ticket: last NRB blocks become the reduce grid -------------------
  __shared__ int stk;
  if (t == 0) {
    __threadfence();  // release partials device-wide before arrival
    stk = atomicAdd(qc, 1);
  }
  __syncthreads();
  int tk0 = stk;
  if (tk0 < NGB - NRB) return;  // early finishers exit
  if (t == 0) {
    while (__hip_atomic_load(qc, __ATOMIC_ACQUIRE, __HIP_MEMORY_SCOPE_AGENT) < NGB)
      __builtin_amdgcn_s_sleep(16);
    __threadfence();  // acquire: all partials visible
  }
  __syncthreads();
  int rblk = tk0 - (NGB - NRB);  // 0..NRB-1

  // ---- reduce slice (R15 reduce_final body, blockIdx -> rblk) ------------------
  float2* lz = (float2*)lds;            // [4][64]
  float2* lc = lz + 256;                // [4][64]
  float* rr = (float*)(lc + 256);       // [2][4]
  int* tkp = (int*)(rr + 8);
  int e2 = rblk * 64 + lane;
  float2 sz = make_float2(0.f, 0.f), sc = make_float2(0.f, 0.f);
  for (int k = 0; k < NPAIR / 4; ++k) {
    size_t c = (size_t)(wave * (NPAIR / 4) + k) * 8192 + e2;
    float2 fz = __half22float2(pz[c]);
    float2 fc = __half22float2(pc[c]);
    sz.x += fz.x; sz.y += fz.y;
    sc.x += fc.x; sc.y += fc.y;
  }
  lz[wave * 64 + lane] = sz;
  lc[wave * 64 + lane] = sc;
  __syncthreads();
  if (wave == 0) {
    float2 tz = make_float2(0.f, 0.f), tc = make_float2(0.f, 0.f);
#pragma unroll
    for (int w = 0; w < 4; ++w) {
      tz.x += lz[w * 64 + lane].x; tz.y += lz[w * 64 + lane].y;
      tc.x += lc[w * 64 + lane].x; tc.y += lc[w * 64 + lane].y;
    }
    float S = wave_sum(tz.x * tc.x + tz.y * tc.y);
    if (lane == 0) {
      unsafeAtomicAdd(&scal[2], S);
      __threadfence();
      tkp[0] = atomicAdd(ticket_p, 1);
    }
  }
  __syncthreads();
  if (tkp[0] == NRB - 1) {  // last reduce block: compose loss, full-block coalesced
    float a1 = 0.f, a2 = 0.f;
#pragma unroll
    for (int k = 0; k < 16; ++k) {
      float2 d = dpart[k * 256 + t];
      a1 += d.x; a2 += d.y;
    }
    a1 = wave_sum(a1);
    a2 = wave_sum(a2);
    if (lane == 0) { rr[wave] = a1; rr[4 + wave] = a2; }
    __syncthreads();
    if (t == 0) {
      float SS = atomicAdd(&scal[2], 0.0f);
      double S1 = (double)rr[0] + rr[1] + rr[2] + rr[3];
      double S2 = (double)rr[4] + rr[5] + rr[6] + rr[7];
      double Sall = SS;
      double B = (double)NC;
      double inv_loss = S2 / (B * B) - 2.0 * S1 / B + (double)NC;
      double red_loss = (Sall - S2) / (B * B);
      out[0] = (float)(inv_loss + (double)LAMBDA * red_loss);
    }
  }
}

extern "C" void kernel_launch(void* const* d_in, const int* in_sizes, int n_in,
                              void* d_out, int out_size, void* d_ws, size_t ws_size,
                              hipStream_t stream) {
  const float* z = (const float*)d_in[0];
  const int* labels = (const int*)d_in[1];
  float* out = (float*)d_out;
  float* ws = (float*)d_ws;

  // ws layout (u32 units):
  // [pz NPAIR*8192 h2][pc NPAIR*8192 h2][znb NC*64 u32][cnb NC*64 u32]
  // [dpart 4096 f2][scal 16 f][cnt NC int][slot NC*SLOTCAP int]
  __half2* pz = (__half2*)ws;
  __half2* pc = pz + (size_t)NPAIR * 8192;
  unsigned* znb = (unsigned*)(pc + (size_t)NPAIR * 8192);
  unsigned* cnb = znb + (size_t)NC * 64;
  float2* dpart = (float2*)(cnb + (size_t)NC * 64);
  float* scal = (float*)(dpart + 4096);
  int* cnt = (int*)(scal + 16);
  int* slot = cnt + NC;
  int* ticket = (int*)&scal[8];
  int* qc = (int*)&scal[12];

  zero_kernel<<<NC / 1024, 256, 0, stream>>>((int4*)cnt, scal);
  scatter_kernel<<<NC / 256, 256, 0, stream>>>(labels, cnt, slot);
  center_kernel<<<NC / 4, 256, 0, stream>>>(z, cnt, slot, cnb, znb, dpart);
  gram_reduce_kernel<<<NGB, 256, 0, stream>>>((const unsigned short*)znb,
                                              (const unsigned short*)cnb, pz, pc,
                                              dpart, scal, ticket, qc, out);
}

// Round 19
// 37.601 us; speedup vs baseline: 1.3570x; 1.3570x over previous
//
#include <hip/hip_runtime.h>
#include <hip/hip_fp16.h>

#define NC 16384        // num classes == batch
#define FD 128          // feature dim
#define LAMBDA 0.005f
#define SLOTCAP 64      // max samples tracked per class (Poisson(1): max ~10)
#define NPAIR 128       // 128-row pairs (2x64 chunks) per matrix

typedef __attribute__((ext_vector_type(8))) short short8;  // 8 bf16 (4 VGPRs)
typedef __attribute__((ext_vector_type(4))) float f32x4;   // MFMA acc

__device__ __forceinline__ float wave_sum(float v) {
#pragma unroll
  for (int m = 32; m > 0; m >>= 1) v += __shfl_xor(v, m, 64);
  return v;
}

__device__ __forceinline__ unsigned pack_bf16(float x, float y) {
  unsigned ux = __float_as_uint(x), uy = __float_as_uint(y);
  ux = (ux + 0x7FFFu + ((ux >> 16) & 1u)) >> 16;  // RNE f32->bf16
  uy = (uy + 0x7FFFu + ((uy >> 16) & 1u)) >> 16;
  return ux | (uy << 16);
}

// --- 1. zero cnt + scal ---------------------------------------------------------
__global__ __launch_bounds__(256) void zero_kernel(int4* __restrict__ cnt4,
                                                   float* __restrict__ scal) {
  cnt4[blockIdx.x * 256 + threadIdx.x] = make_int4(0, 0, 0, 0);
  if (blockIdx.x == 0 && threadIdx.x < 16) scal[threadIdx.x] = 0.f;
}

// --- 2. scatter: slot[lab][k] = sample index --------------------------------------
__global__ __launch_bounds__(256) void scatter_kernel(
    const int* __restrict__ labels, int* __restrict__ cnt, int* __restrict__ slot) {
  int i = blockIdx.x * 256 + threadIdx.x;
  int lab = labels[i];
  int p = atomicAdd(&cnt[lab], 1);
  if (p < SLOTCAP) slot[(size_t)lab * SLOTCAP + p] = i;
}

// --- 3. centers + diag -> bf16 zn/cn; parallel-issued load chain -------------------
__global__ __launch_bounds__(256) void center_kernel(
    const float* __restrict__ z, const int* __restrict__ cnt,
    const int* __restrict__ slot, unsigned* __restrict__ cnb,
    unsigned* __restrict__ znb, float2* __restrict__ dpart) {
  __shared__ float red[8];
  int t = threadIdx.x, wave = t >> 6, lane = t & 63;
  int c = blockIdx.x * 4 + wave;

  // independent loads issued together: slot int4, cnt, diag z row
  int4 s4 = *(const int4*)&slot[(size_t)c * SLOTCAP];
  int n = cnt[c];
  float2 a = *(const float2*)&z[(size_t)c * FD + lane * 2];
  if (n > SLOTCAP) n = SLOTCAP;

  // up to 4 gathered rows in parallel (predicated index; safe dummy = row c)
  int i0 = n > 0 ? s4.x : c, i1 = n > 1 ? s4.y : c;
  int i2 = n > 2 ? s4.z : c, i3 = n > 3 ? s4.w : c;
  float2 v0 = *(const float2*)&z[(size_t)i0 * FD + lane * 2];
  float2 v1 = *(const float2*)&z[(size_t)i1 * FD + lane * 2];
  float2 v2 = *(const float2*)&z[(size_t)i2 * FD + lane * 2];
  float2 v3 = *(const float2*)&z[(size_t)i3 * FD + lane * 2];
  float2 s = make_float2(0.f, 0.f);
  if (n > 0) { s.x += v0.x; s.y += v0.y; }
  if (n > 1) { s.x += v1.x; s.y += v1.y; }
  if (n > 2) { s.x += v2.x; s.y += v2.y; }
  if (n > 3) { s.x += v3.x; s.y += v3.y; }
  for (int k = 4; k < n; ++k) {  // rare (Poisson(1) tail)
    int i = slot[(size_t)c * SLOTCAP + k];
    float2 v = *(const float2*)&z[(size_t)i * FD + lane * 2];
    s.x += v.x; s.y += v.y;
  }
  float inv = n > 0 ? 1.0f / (float)n : 0.0f;
  s.x *= inv; s.y *= inv;
  float sc = wave_sum(s.x * s.x + s.y * s.y);
  float ic = 1.0f / fmaxf(sqrtf(sc), 1e-12f);
  s.x *= ic; s.y *= ic;
  cnb[(size_t)c * 64 + lane] = pack_bf16(s.x, s.y);

  // diag + normalized z row out
  float na = wave_sum(a.x * a.x + a.y * a.y);
  float ia = 1.0f / fmaxf(sqrtf(na), 1e-12f);
  float dd = wave_sum(a.x * s.x + a.y * s.y);
  float d = dd * ia;
  znb[(size_t)c * 64 + lane] = pack_bf16(a.x * ia, a.y * ia);

  if (lane == 0) { red[wave * 2] = d; red[wave * 2 + 1] = d * d; }
  __syncthreads();
  if (t == 0) {
    dpart[blockIdx.x] = make_float2(red[0] + red[2] + red[4] + red[6],
                                    red[1] + red[3] + red[5] + red[7]);
  }
}

// --- 4. gram partials via MFMA: 2 chunks (128 rows) accumulated per block ----------
// block b: matrix m=b&1 (0->znb, 1->cnb), pair=b>>1. G = T^T T over rows
// [pair*128, pair*128+128). bf16 tiles B0/B1 [64][130]; G fp16 [128][130] aliases.
__global__ __launch_bounds__(256) void gram_kernel(
    const unsigned short* __restrict__ znb, const unsigned short* __restrict__ cnb,
    __half2* __restrict__ pz, __half2* __restrict__ pc) {
  __shared__ char lds[33280];
  unsigned short* Bu = (unsigned short*)lds;  // B0 @0, B1 @8320 (u16 units)
  int t = threadIdx.x, wave = t >> 6, lane = t & 63;
  int b = blockIdx.x, m = b & 1, pair = b >> 1;
  const unsigned short* Ab = m ? cnb : znb;

  {  // stage both 64x128 bf16 chunks, coalesced int4 (32 KB total)
    const int4* src = (const int4*)(Ab + (size_t)pair * 16384);
#pragma unroll
    for (int k = 0; k < 8; ++k) {
      int idx = k * 256 + t;
      int q = idx >> 10, idx2 = idx & 1023;
      int row = idx2 >> 4, col8 = idx2 & 15;
      *(int4*)&Bu[q * 8320 + row * 130 + col8 * 8] = src[idx];
    }
  }
  __syncthreads();

  f32x4 acc[2][8];
#pragma unroll
  for (int i = 0; i < 2; ++i)
#pragma unroll
    for (int j = 0; j < 8; ++j)
      acc[i][j] = (f32x4){0.f, 0.f, 0.f, 0.f};

#pragma unroll
  for (int q = 0; q < 2; ++q) {
    const unsigned short* Bl = Bu + q * 8320 + (lane >> 4) * (8 * 130) + (lane & 15);
    short8 fr[2][8];
#pragma unroll
    for (int kb = 0; kb < 2; ++kb)
#pragma unroll
      for (int cb = 0; cb < 8; ++cb)
#pragma unroll
        for (int j = 0; j < 8; ++j)
          fr[kb][cb][j] = (short)Bl[kb * 4160 + cb * 16 + j * 130];
    short8 fa[2][2];
#pragma unroll
    for (int til = 0; til < 2; ++til)
#pragma unroll
      for (int kb = 0; kb < 2; ++kb)
#pragma unroll
        for (int j = 0; j < 8; ++j)
          fa[til][kb][j] = (short)Bl[kb * 4160 + (wave * 2 + til) * 16 + j * 130];
#pragma unroll
    for (int til = 0; til < 2; ++til)
#pragma unroll
      for (int tj = 0; tj < 8; ++tj) {
        acc[til][tj] = __builtin_amdgcn_mfma_f32_16x16x32_bf16(
            fa[til][0], fr[0][tj], acc[til][tj], 0, 0, 0);
        acc[til][tj] = __builtin_amdgcn_mfma_f32_16x16x32_bf16(
            fa[til][1], fr[1][tj], acc[til][tj], 0, 0, 0);
      }
  }
  __syncthreads();  // all frag reads done; safe to alias G over B0/B1

  unsigned short* G = (unsigned short*)lds;  // fp16 [128][130]
#pragma unroll
  for (int til = 0; til < 2; ++til)
#pragma unroll
    for (int tj = 0; tj < 8; ++tj)
#pragma unroll
      for (int q = 0; q < 4; ++q) {
        int d = (wave * 2 + til) * 16 + (lane >> 4) * 4 + q;  // C/D: row=(l>>4)*4+reg
        int e = tj * 16 + (lane & 15);                        //      col=l&15
        __half h = __float2half(acc[til][tj][q]);
        G[d * 130 + e] = *(unsigned short*)&h;
      }
  __syncthreads();

  // coalesced copy-out: [128][64 half2] row-major
  unsigned* Pg = (unsigned*)((m ? pc : pz) + (size_t)pair * 8192);
#pragma unroll
  for (int it = 0; it < 32; ++it) {
    int row = it * 4 + (t >> 6);
    int h2i = t & 63;
    Pg[row * 64 + h2i] = *(const unsigned*)(lds + row * 260 + h2i * 4);
  }
}

// --- 5. reduce fp16 partials + Frobenius + loss (ticket; full-block last sum) ------
__global__ __launch_bounds__(256) void reduce_final_kernel(
    const __half2* __restrict__ pz, const __half2* __restrict__ pc,
    const float2* __restrict__ dpart, float* __restrict__ scal,
    int* __restrict__ ticket_p, float* __restrict__ out) {
  __shared__ float2 lz[4][64], lc[4][64];
  __shared__ float rr[2][4];
  __shared__ int tk;
  int t = threadIdx.x, wave = t >> 6, lane = t & 63;
  int e2 = blockIdx.x * 64 + lane;  // half2 index in [0, 8192)
  float2 sz = make_float2(0.f, 0.f), sc = make_float2(0.f, 0.f);
  for (int k = 0; k < NPAIR / 4; ++k) {
    size_t c = (size_t)(wave * (NPAIR / 4) + k) * 8192 + e2;
    float2 fz = __half22float2(pz[c]);
    float2 fc = __half22float2(pc[c]);
    sz.x += fz.x; sz.y += fz.y;
    sc.x += fc.x; sc.y += fc.y;
  }
  lz[wave][lane] = sz;
  lc[wave][lane] = sc;
  __syncthreads();
  if (wave == 0) {
    float2 tz = make_float2(0.f, 0.f), tc = make_float2(0.f, 0.f);
#pragma unroll
    for (int w = 0; w < 4; ++w) {
      tz.x += lz[w][lane].x; tz.y += lz[w][lane].y;
      tc.x += lc[w][lane].x; tc.y += lc[w][lane].y;
    }
    float S = wave_sum(tz.x * tc.x + tz.y * tc.y);
    if (lane == 0) {
      unsafeAtomicAdd(&scal[2], S);
      __threadfence();
      tk = atomicAdd(ticket_p, 1);
    }
  }
  __syncthreads();
  if (tk == 127) {  // last block: compose loss with all 256 threads coalesced
    float a1 = 0.f, a2 = 0.f;
#pragma unroll
    for (int k = 0; k < 16; ++k) {
      float2 d = dpart[k * 256 + t];
      a1 += d.x; a2 += d.y;
    }
    a1 = wave_sum(a1);
    a2 = wave_sum(a2);
    if (lane == 0) { rr[0][wave] = a1; rr[1][wave] = a2; }
    __syncthreads();
    if (t == 0) {
      float SS = atomicAdd(&scal[2], 0.0f);
      double S1 = (double)rr[0][0] + rr[0][1] + rr[0][2] + rr[0][3];
      double S2 = (double)rr[1][0] + rr[1][1] + rr[1][2] + rr[1][3];
      double Sall = SS;
      double B = (double)NC;
      double inv_loss = S2 / (B * B) - 2.0 * S1 / B + (double)NC;
      double red_loss = (Sall - S2) / (B * B);
      out[0] = (float)(inv_loss + (double)LAMBDA * red_loss);
    }
  }
}

extern "C" void kernel_launch(void* const* d_in, const int* in_sizes, int n_in,
                              void* d_out, int out_size, void* d_ws, size_t ws_size,
                              hipStream_t stream) {
  const float* z = (const float*)d_in[0];
  const int* labels = (const int*)d_in[1];
  float* out = (float*)d_out;
  float* ws = (float*)d_ws;

  // ws layout (u32 units):
  // [pz NPAIR*8192 h2][pc NPAIR*8192 h2][znb NC*64 u32][cnb NC*64 u32]
  // [dpart 4096 f2][scal 16 f][cnt NC int][slot NC*SLOTCAP int]
  __half2* pz = (__half2*)ws;
  __half2* pc = pz + (size_t)NPAIR * 8192;
  unsigned* znb = (unsigned*)(pc + (size_t)NPAIR * 8192);
  unsigned* cnb = znb + (size_t)NC * 64;
  float2* dpart = (float2*)(cnb + (size_t)NC * 64);
  float* scal = (float*)(dpart + 4096);
  int* cnt = (int*)(scal + 16);
  int* slot = cnt + NC;
  int* ticket = (int*)&scal[8];

  zero_kernel<<<NC / 1024, 256, 0, stream>>>((int4*)cnt, scal);
  scatter_kernel<<<NC / 256, 256, 0, stream>>>(labels, cnt, slot);
  center_kernel<<<NC / 4, 256, 0, stream>>>(z, cnt, slot, cnb, znb, dpart);
  gram_kernel<<<2 * NPAIR, 256, 0, stream>>>((const unsigned short*)znb,
                                             (const unsigned short*)cnb, pz, pc);
  reduce_final_kernel<<<128, 256, 0, stream>>>(pz, pc, dpart, scal, ticket, out);
}

// Round 20
// 37.415 us; speedup vs baseline: 1.3638x; 1.0050x over previous
//
#include <hip/hip_runtime.h>
#include <hip/hip_fp16.h>

#define NC 16384        // num classes == batch
#define FD 128          // feature dim
#define LAMBDA 0.005f
#define SLOTCAP 64      // max samples tracked per class (Poisson(1): max ~10)
#define NQUAD 64        // 256-row quads (4x64 chunks) per matrix

typedef __attribute__((ext_vector_type(8))) short short8;  // 8 bf16 (4 VGPRs)
typedef __attribute__((ext_vector_type(4))) float f32x4;   // MFMA acc

__device__ __forceinline__ float wave_sum(float v) {
#pragma unroll
  for (int m = 32; m > 0; m >>= 1) v += __shfl_xor(v, m, 64);
  return v;
}

__device__ __forceinline__ unsigned pack_bf16(float x, float y) {
  unsigned ux = __float_as_uint(x), uy = __float_as_uint(y);
  ux = (ux + 0x7FFFu + ((ux >> 16) & 1u)) >> 16;  // RNE f32->bf16
  uy = (uy + 0x7FFFu + ((uy >> 16) & 1u)) >> 16;
  return ux | (uy << 16);
}

// --- 1. zero cnt + scal ---------------------------------------------------------
__global__ __launch_bounds__(256) void zero_kernel(int4* __restrict__ cnt4,
                                                   float* __restrict__ scal) {
  cnt4[blockIdx.x * 256 + threadIdx.x] = make_int4(0, 0, 0, 0);
  if (blockIdx.x == 0 && threadIdx.x < 16) scal[threadIdx.x] = 0.f;
}

// --- 2. scatter: slot[lab][k] = sample index --------------------------------------
__global__ __launch_bounds__(256) void scatter_kernel(
    const int* __restrict__ labels, int* __restrict__ cnt, int* __restrict__ slot) {
  int i = blockIdx.x * 256 + threadIdx.x;
  int lab = labels[i];
  int p = atomicAdd(&cnt[lab], 1);
  if (p < SLOTCAP) slot[(size_t)lab * SLOTCAP + p] = i;
}

// --- 3. centers + diag -> bf16 zn/cn; parallel-issued load chain (R15 verbatim) ----
__global__ __launch_bounds__(256) void center_kernel(
    const float* __restrict__ z, const int* __restrict__ cnt,
    const int* __restrict__ slot, unsigned* __restrict__ cnb,
    unsigned* __restrict__ znb, float2* __restrict__ dpart) {
  __shared__ float red[8];
  int t = threadIdx.x, wave = t >> 6, lane = t & 63;
  int c = blockIdx.x * 4 + wave;

  // independent loads issued together: slot int4, cnt, diag z row
  int4 s4 = *(const int4*)&slot[(size_t)c * SLOTCAP];
  int n = cnt[c];
  float2 a = *(const float2*)&z[(size_t)c * FD + lane * 2];
  if (n > SLOTCAP) n = SLOTCAP;

  // up to 4 gathered rows in parallel (predicated index; safe dummy = row c)
  int i0 = n > 0 ? s4.x : c, i1 = n > 1 ? s4.y : c;
  int i2 = n > 2 ? s4.z : c, i3 = n > 3 ? s4.w : c;
  float2 v0 = *(const float2*)&z[(size_t)i0 * FD + lane * 2];
  float2 v1 = *(const float2*)&z[(size_t)i1 * FD + lane * 2];
  float2 v2 = *(const float2*)&z[(size_t)i2 * FD + lane * 2];
  float2 v3 = *(const float2*)&z[(size_t)i3 * FD + lane * 2];
  float2 s = make_float2(0.f, 0.f);
  if (n > 0) { s.x += v0.x; s.y += v0.y; }
  if (n > 1) { s.x += v1.x; s.y += v1.y; }
  if (n > 2) { s.x += v2.x; s.y += v2.y; }
  if (n > 3) { s.x += v3.x; s.y += v3.y; }
  for (int k = 4; k < n; ++k) {  // rare (Poisson(1) tail)
    int i = slot[(size_t)c * SLOTCAP + k];
    float2 v = *(const float2*)&z[(size_t)i * FD + lane * 2];
    s.x += v.x; s.y += v.y;
  }
  float inv = n > 0 ? 1.0f / (float)n : 0.0f;
  s.x *= inv; s.y *= inv;
  float sc = wave_sum(s.x * s.x + s.y * s.y);
  float ic = 1.0f / fmaxf(sqrtf(sc), 1e-12f);
  s.x *= ic; s.y *= ic;
  cnb[(size_t)c * 64 + lane] = pack_bf16(s.x, s.y);

  // diag + normalized z row out
  float na = wave_sum(a.x * a.x + a.y * a.y);
  float ia = 1.0f / fmaxf(sqrtf(na), 1e-12f);
  float dd = wave_sum(a.x * s.x + a.y * s.y);
  float d = dd * ia;
  znb[(size_t)c * 64 + lane] = pack_bf16(a.x * ia, a.y * ia);

  if (lane == 0) { red[wave * 2] = d; red[wave * 2 + 1] = d * d; }
  __syncthreads();
  if (t == 0) {
    dpart[blockIdx.x] = make_float2(red[0] + red[2] + red[4] + red[6],
                                    red[1] + red[3] + red[5] + red[7]);
  }
}

// --- 4. gram partials via MFMA: 4 chunks (256 rows) accumulated per block ----------
// block b: matrix m=b&1 (0->znb, 1->cnb), quad=b>>1. Two stage->compute passes
// over B0/B1 [64][130]; accumulators persist; G fp16 [128][130] aliases after.
__global__ __launch_bounds__(256) void gram_kernel(
    const unsigned short* __restrict__ znb, const unsigned short* __restrict__ cnb,
    __half2* __restrict__ pz, __half2* __restrict__ pc) {
  __shared__ char lds[33280];
  unsigned short* Bu = (unsigned short*)lds;  // B0 @0, B1 @8320 (u16 units)
  int t = threadIdx.x, wave = t >> 6, lane = t & 63;
  int b = blockIdx.x, m = b & 1, quad = b >> 1;
  const unsigned short* Ab = m ? cnb : znb;

  f32x4 acc[2][8];
#pragma unroll
  for (int i = 0; i < 2; ++i)
#pragma unroll
    for (int j = 0; j < 8; ++j)
      acc[i][j] = (f32x4){0.f, 0.f, 0.f, 0.f};

#pragma unroll
  for (int half = 0; half < 2; ++half) {
    int pair = quad * 2 + half;
    {  // stage two 64x128 bf16 chunks, coalesced int4 (32 KB)
      const int4* src = (const int4*)(Ab + (size_t)pair * 16384);
#pragma unroll
      for (int k = 0; k < 8; ++k) {
        int idx = k * 256 + t;
        int q = idx >> 10, idx2 = idx & 1023;
        int row = idx2 >> 4, col8 = idx2 & 15;
        *(int4*)&Bu[q * 8320 + row * 130 + col8 * 8] = src[idx];
      }
    }
    __syncthreads();

#pragma unroll
    for (int q = 0; q < 2; ++q) {
      const unsigned short* Bl = Bu + q * 8320 + (lane >> 4) * (8 * 130) + (lane & 15);
      short8 fr[2][8];
#pragma unroll
      for (int kb = 0; kb < 2; ++kb)
#pragma unroll
        for (int cb = 0; cb < 8; ++cb)
#pragma unroll
          for (int j = 0; j < 8; ++j)
            fr[kb][cb][j] = (short)Bl[kb * 4160 + cb * 16 + j * 130];
      short8 fa[2][2];
#pragma unroll
      for (int til = 0; til < 2; ++til)
#pragma unroll
        for (int kb = 0; kb < 2; ++kb)
#pragma unroll
          for (int j = 0; j < 8; ++j)
            fa[til][kb][j] = (short)Bl[kb * 4160 + (wave * 2 + til) * 16 + j * 130];
#pragma unroll
      for (int til = 0; til < 2; ++til)
#pragma unroll
        for (int tj = 0; tj < 8; ++tj) {
          acc[til][tj] = __builtin_amdgcn_mfma_f32_16x16x32_bf16(
              fa[til][0], fr[0][tj], acc[til][tj], 0, 0, 0);
          acc[til][tj] = __builtin_amdgcn_mfma_f32_16x16x32_bf16(
              fa[til][1], fr[1][tj], acc[til][tj], 0, 0, 0);
        }
    }
    __syncthreads();  // frag reads done; safe to restage (or alias G after loop)
  }

  unsigned short* G = (unsigned short*)lds;  // fp16 [128][130]
#pragma unroll
  for (int til = 0; til < 2; ++til)
#pragma unroll
    for (int tj = 0; tj < 8; ++tj)
#pragma unroll
      for (int q = 0; q < 4; ++q) {
        int d = (wave * 2 + til) * 16 + (lane >> 4) * 4 + q;  // C/D: row=(l>>4)*4+reg
        int e = tj * 16 + (lane & 15);                        //      col=l&15
        __half h = __float2half(acc[til][tj][q]);
        G[d * 130 + e] = *(unsigned short*)&h;
      }
  __syncthreads();

  // coalesced copy-out: [128][64 half2] row-major
  unsigned* Pg = (unsigned*)((m ? pc : pz) + (size_t)quad * 8192);
#pragma unroll
  for (int it = 0; it < 32; ++it) {
    int row = it * 4 + (t >> 6);
    int h2i = t & 63;
    Pg[row * 64 + h2i] = *(const unsigned*)(lds + row * 260 + h2i * 4);
  }
}

// --- 5. reduce fp16 partials + Frobenius + loss (ticket; full-block last sum) ------
__global__ __launch_bounds__(256) void reduce_final_kernel(
    const __half2* __restrict__ pz, const __half2* __restrict__ pc,
    const float2* __restrict__ dpart, float* __restrict__ scal,
    int* __restrict__ ticket_p, float* __restrict__ out) {
  __shared__ float2 lz[4][64], lc[4][64];
  __shared__ float rr[2][4];
  __shared__ int tk;
  int t = threadIdx.x, wave = t >> 6, lane = t & 63;
  int e2 = blockIdx.x * 64 + lane;  // half2 index in [0, 8192)
  float2 sz = make_float2(0.f, 0.f), sc = make_float2(0.f, 0.f);
  for (int k = 0; k < NQUAD / 4; ++k) {
    size_t c = (size_t)(wave * (NQUAD / 4) + k) * 8192 + e2;
    float2 fz = __half22float2(pz[c]);
    float2 fc = __half22float2(pc[c]);
    sz.x += fz.x; sz.y += fz.y;
    sc.x += fc.x; sc.y += fc.y;
  }
  lz[wave][lane] = sz;
  lc[wave][lane] = sc;
  __syncthreads();
  if (wave == 0) {
    float2 tz = make_float2(0.f, 0.f), tc = make_float2(0.f, 0.f);
#pragma unroll
    for (int w = 0; w < 4; ++w) {
      tz.x += lz[w][lane].x; tz.y += lz[w][lane].y;
      tc.x += lc[w][lane].x; tc.y += lc[w][lane].y;
    }
    float S = wave_sum(tz.x * tc.x + tz.y * tc.y);
    if (lane == 0) {
      unsafeAtomicAdd(&scal[2], S);
      __threadfence();
      tk = atomicAdd(ticket_p, 1);
    }
  }
  __syncthreads();
  if (tk == 127) {  // last block: compose loss with all 256 threads coalesced
    float a1 = 0.f, a2 = 0.f;
#pragma unroll
    for (int k = 0; k < 16; ++k) {
      float2 d = dpart[k * 256 + t];
      a1 += d.x; a2 += d.y;
    }
    a1 = wave_sum(a1);
    a2 = wave_sum(a2);
    if (lane == 0) { rr[0][wave] = a1; rr[1][wave] = a2; }
    __syncthreads();
    if (t == 0) {
      float SS = atomicAdd(&scal[2], 0.0f);
      double S1 = (double)rr[0][0] + rr[0][1] + rr[0][2] + rr[0][3];
      double S2 = (double)rr[1][0] + rr[1][1] + rr[1][2] + rr[1][3];
      double Sall = SS;
      double B = (double)NC;
      double inv_loss = S2 / (B * B) - 2.0 * S1 / B + (double)NC;
      double red_loss = (Sall - S2) / (B * B);
      out[0] = (float)(inv_loss + (double)LAMBDA * red_loss);
    }
  }
}

extern "C" void kernel_launch(void* const* d_in, const int* in_sizes, int n_in,
                              void* d_out, int out_size, void* d_ws, size_t ws_size,
                              hipStream_t stream) {
  const float* z = (const float*)d_in[0];
  const int* labels = (const int*)d_in[1];
  float* out = (float*)d_out;
  float* ws = (float*)d_ws;

  // ws layout (u32 units):
  // [pz NQUAD*8192 h2][pc NQUAD*8192 h2][znb NC*64 u32][cnb NC*64 u32]
  // [dpart 4096 f2][scal 16 f][cnt NC int][slot NC*SLOTCAP int]
  __half2* pz = (__half2*)ws;
  __half2* pc = pz + (size_t)NQUAD * 8192;
  unsigned* znb = (unsigned*)(pc + (size_t)NQUAD * 8192);
  unsigned* cnb = znb + (size_t)NC * 64;
  float2* dpart = (float2*)(cnb + (size_t)NC * 64);
  float* scal = (float*)(dpart + 4096);
  int* cnt = (int*)(scal + 16);
  int* slot = cnt + NC;
  int* ticket = (int*)&scal[8];

  zero_kernel<<<NC / 1024, 256, 0, stream>>>((int4*)cnt, scal);
  scatter_kernel<<<NC / 256, 256, 0, stream>>>(labels, cnt, slot);
  center_kernel<<<NC / 4, 256, 0, stream>>>(z, cnt, slot, cnb, znb, dpart);
  gram_kernel<<<2 * NQUAD, 256, 0, stream>>>((const unsigned short*)znb,
                                             (const unsigned short*)cnb, pz, pc);
  reduce_final_kernel<<<128, 256, 0, stream>>>(pz, pc, dpart, scal, ticket, out);
}